// Round 2
// baseline (637.705 us; speedup 1.0000x reference)
//
#include <hip/hip_runtime.h>

// ---------- problem constants ----------
#define HW_   576
#define BHW   1152      // B*HW
#define DD    2048
#define CLIPC 1024
#define NSEQ  768
#define LL    25

typedef __bf16 bf16x8 __attribute__((ext_vector_type(8)));
typedef float  f32x4  __attribute__((ext_vector_type(4)));
typedef unsigned short u16;

__device__ __forceinline__ float bf2f(u16 u){
  union { unsigned int i; float f; } v; v.i = ((unsigned int)u) << 16; return v.f;
}
__device__ __forceinline__ u16 f2bf(float f){
  union { float f; unsigned int i; } v; v.f = f;
  unsigned int u = v.i;
  return (u16)((u + 0x7fffu + ((u >> 16) & 1u)) >> 16);  // RNE
}

// async global->LDS, 16B per lane; LDS dest = wave-uniform base + lane*16
__device__ __forceinline__ void gld_lds16(const void* g, void* l){
  __builtin_amdgcn_global_load_lds((__attribute__((address_space(1))) void*)g,
                                   (__attribute__((address_space(3))) void*)l,
                                   16, 0, 0);
}

// ---------- setup: image-token index per sample + zero the cos accumulator ----------
__global__ void setup_k(const int* __restrict__ ids, int* __restrict__ idxbuf,
                        float* __restrict__ acc){
  const int lane = threadIdx.x;
  for (int b = 0; b < 2; b++){
    int best = 0x7fffffff;
    for (int i = lane; i < NSEQ; i += 64)
      if (ids[b*NSEQ + i] == -200 && i < best) best = i;
    for (int off = 32; off; off >>= 1){ int o = __shfl_xor(best, off); best = min(best, o); }
    if (lane == 0) idxbuf[b] = best;
  }
  if (lane == 0) acc[0] = 0.f;
}

// ---------- fp32 -> bf16 weight conversion (norm_w || input_w -> B_all; output_w -> outw) ----------
__global__ void conv_weights(const float* __restrict__ norm_w, const float* __restrict__ input_w,
                             const float* __restrict__ output_w, u16* __restrict__ B_all,
                             u16* __restrict__ outw){
  const long n1 = 7L*CLIPC*DD, n2 = (long)CLIPC*DD, n3 = (long)CLIPC*CLIPC;
  long idx = ((long)blockIdx.x*256 + threadIdx.x) * 4;
  if (idx >= n1 + n2 + n3) return;
  const float* s; u16* d;
  if (idx < n1)         { s = norm_w  + idx;            d = B_all + idx; }
  else if (idx < n1+n2) { s = input_w + (idx - n1);     d = B_all + idx; }
  else                  { s = output_w + (idx - n1 - n2); d = outw + (idx - n1 - n2); }
  float4 v = *(const float4*)s;
  union { u16 u[4]; unsigned long long q; } pk;
  pk.u[0] = f2bf(v.x); pk.u[1] = f2bf(v.y); pk.u[2] = f2bf(v.z); pk.u[3] = f2bf(v.w);
  *(unsigned long long*)d = pk.q;
}

// ---------- clip_w (1024 x 588) -> bf16 padded to K=608 ----------
__global__ void conv_clipw(const float* __restrict__ clip_w, u16* __restrict__ dst){
  const int c = blockIdx.x, tid = threadIdx.x;
  for (int k = tid; k < 608; k += 128)
    dst[c*608 + k] = (k < 588) ? f2bf(clip_w[c*588 + k]) : (u16)0;
}

// ---------- patchify images -> bf16 [1152][608] (K padded) ----------
__global__ void conv_patches(const float* __restrict__ images, u16* __restrict__ dst){
  const int r = blockIdx.x, tid = threadIdx.x;
  const int b = r / HW_, n = r % HW_;
  const int hi = n / 24, wi = n % 24;
  for (int p = tid; p < 608; p += 128){
    float v = 0.f;
    if (p < 588){
      int c3 = p / 196, rem = p - c3*196;
      int ph = rem / 14, pw = rem - ph*14;
      v = images[(((long)b*4 + c3)*336 + hi*14 + ph)*336 + wi*14 + pw];
    }
    dst[(long)r*608 + p] = f2bf(v);
  }
}

// ---------- gather token slice + LayerNorm -> A_all bf16 (slots 0..6 LN'd layers, slot 7 raw layer 24) ----------
__global__ void gather_ln(const float* __restrict__ feats, const int* __restrict__ idxbuf,
                          const float* __restrict__ gamma, const float* __restrict__ beta,
                          u16* __restrict__ A_all){
  const int r = blockIdx.x, g = blockIdx.y;
  const int b = r / HW_, n = r % HW_;
  const int hi = n / 24, wi = n % 24;
  const int tok = idxbuf[b] + 1 + hi*25 + wi;
  const int layer = (g < 7) ? (24 - g*4) : 24;
  const float* src = feats + (((long)(b*NSEQ + tok))*LL + layer)*DD;
  const int tid = threadIdx.x;
  float v[8];
#pragma unroll
  for (int k = 0; k < 8; k++) v[k] = src[tid + k*256];
  u16* dst = A_all + ((long)g*BHW + r)*DD;
  if (g == 7){
#pragma unroll
    for (int k = 0; k < 8; k++) dst[tid + k*256] = f2bf(v[k]);
    return;
  }
  float s = 0.f, q = 0.f;
#pragma unroll
  for (int k = 0; k < 8; k++){ s += v[k]; q += v[k]*v[k]; }
  for (int off = 32; off; off >>= 1){ s += __shfl_xor(s, off); q += __shfl_xor(q, off); }
  __shared__ float rs[4], rq[4];
  const int wave = tid >> 6, lane = tid & 63;
  if (lane == 0){ rs[wave] = s; rq[wave] = q; }
  __syncthreads();
  const float ts = rs[0]+rs[1]+rs[2]+rs[3];
  const float tq = rq[0]+rq[1]+rq[2]+rq[3];
  const float mu   = ts * (1.f/2048.f);
  const float var  = tq * (1.f/2048.f) - mu*mu;
  const float rstd = rsqrtf(var + 1e-5f);
  const float* gm = gamma + g*DD;
  const float* bt = beta  + g*DD;
#pragma unroll
  for (int k = 0; k < 8; k++){
    int d = tid + k*256;
    dst[d] = f2bf((v[k]-mu)*rstd*gm[d] + bt[d]);
  }
}

// ---------- MFMA GEMM: C[z] = A[z] (MxK, row-major) * B[z]^T (B is NxK row-major) ----------
// 128x128 tile, BK=32, 4 waves (each 64x64 via 4x4 of 16x16x32 MFMA), m97-style 2-barrier K-loop.
// __launch_bounds__(256,3): 3 blocks/CU (12 waves/CU) — the m97 occupancy; (256,2) exposed the
// barrier-drain stall (wave-level overlap across blocks is what hides vmcnt(0)+s_barrier).
template<bool OUT_BF16>
__global__ __launch_bounds__(256, 3)
void gemm_bt(const u16* __restrict__ A, const u16* __restrict__ B,
             void* __restrict__ Cv, const float* __restrict__ bias, int bias_z,
             const u16* __restrict__ addsrc,
             int N, int K, long aSlot, long bSlot, long cSlot){
  const int z = blockIdx.z;
  const u16* Az = A + (long)z * aSlot;
  const u16* Bz = B + (long)z * bSlot;
  const int bm = blockIdx.x * 128;
  const int bn = blockIdx.y * 128;
  __shared__ alignas(16) u16 As[128*32];
  __shared__ alignas(16) u16 Bs[128*32];
  const int tid  = threadIdx.x;
  const int wave = tid >> 6, lane = tid & 63;
  const int wr = (wave >> 1) * 64, wc = (wave & 1) * 64;
  const int l15 = lane & 15, quad = lane >> 4;

  f32x4 acc[4][4] = {};

  // staging addressing: wave w stages rows [w*32, w*32+32) of both tiles, 2 insts x 16 rows
  const int  sRow = wave*32 + (lane >> 2);
  const int  sK   = (lane & 3) * 8;
  const u16* gA = Az + (long)(bm + sRow)*K + sK;
  const u16* gB = Bz + (long)(bn + sRow)*K + sK;
  const long r16 = (long)16 * K;
  u16* lA0 = &As[wave*1024]; u16* lA1 = lA0 + 512;
  u16* lB0 = &Bs[wave*1024]; u16* lB1 = lB0 + 512;

  for (int k0 = 0; k0 < K; k0 += 32){
    gld_lds16(gA + k0,        lA0);
    gld_lds16(gA + r16 + k0,  lA1);
    gld_lds16(gB + k0,        lB0);
    gld_lds16(gB + r16 + k0,  lB1);
    __syncthreads();                       // drains vmcnt then barrier
    bf16x8 af[4], bg[4];
#pragma unroll
    for (int i = 0; i < 4; i++) af[i] = *(const bf16x8*)&As[(wr + i*16 + l15)*32 + quad*8];
#pragma unroll
    for (int j = 0; j < 4; j++) bg[j] = *(const bf16x8*)&Bs[(wc + j*16 + l15)*32 + quad*8];
#pragma unroll
    for (int i = 0; i < 4; i++)
#pragma unroll
      for (int j = 0; j < 4; j++)
        acc[i][j] = __builtin_amdgcn_mfma_f32_16x16x32_bf16(af[i], bg[j], acc[i][j], 0, 0, 0);
    __syncthreads();                       // all waves done reading before next stage
  }

  const bool do_bias = (bias != nullptr) && (z == bias_z);
  const long cz = (long)z * cSlot;
#pragma unroll
  for (int i = 0; i < 4; i++)
#pragma unroll
    for (int j = 0; j < 4; j++)
#pragma unroll
      for (int rr = 0; rr < 4; rr++){
        const int row = bm + wr + i*16 + quad*4 + rr;   // C/D: row = quad*4+reg
        const int col = bn + wc + j*16 + l15;           //      col = lane&15
        float v = acc[i][j][rr];
        if (do_bias) v += bias[col];
        if (addsrc)  v += bf2f(addsrc[cz + (long)row*N + col]);
        if constexpr (OUT_BF16) ((u16*)Cv)[cz + (long)row*N + col] = f2bf(v);
        else                    ((float*)Cv)[cz + (long)row*N + col] = v;
      }
}

// ---------- attention: 256 threads = 4 heads (one wave per head pair-slice) ----------
__global__ void attn_k(const u16* __restrict__ C_all, u16* __restrict__ fuse){
  const int r = blockIdx.x;
  const int h = (blockIdx.y << 2) | (threadIdx.x >> 6);   // 4 heads per block
  const int lane = threadIdx.x & 63;
  const long slot = (long)BHW * CLIPC;
  const long rb = (long)r * CLIPC;
  const int c0 = h*128 + lane, c1 = c0 + 64;
  const float q0 = bf2f(C_all[rb + c0]), q1 = bf2f(C_all[rb + c1]);
  float k0v[6], k1v[6], dt[6];
#pragma unroll
  for (int t = 0; t < 6; t++){
    const u16* base = C_all + (long)(t+1)*slot + rb;
    k0v[t] = bf2f(base[c0]); k1v[t] = bf2f(base[c1]);
    dt[t] = q0*k0v[t] + q1*k1v[t];
  }
#pragma unroll
  for (int t = 0; t < 6; t++)
    for (int off = 32; off; off >>= 1) dt[t] += __shfl_xor(dt[t], off);
  float l[6], e[6];
#pragma unroll
  for (int t = 0; t < 6; t++) l[t] = dt[t] * 0.03125f;   // SCALE = 1024^-0.5
  float m = l[0];
#pragma unroll
  for (int t = 1; t < 6; t++) m = fmaxf(m, l[t]);
  float ssum = 0.f;
#pragma unroll
  for (int t = 0; t < 6; t++){ e[t] = __expf(l[t] - m); ssum += e[t]; }
  const float inv = 1.f / ssum;
  float f0 = 0.f, f1 = 0.f;
#pragma unroll
  for (int t = 0; t < 6; t++){ const float a = e[t]*inv; f0 += a*k0v[t]; f1 += a*k1v[t]; }
  fuse[rb + c0] = f2bf(f0);
  fuse[rb + c1] = f2bf(f1);
}

// ---------- cosine per row, accumulate sum of cos ----------
__global__ void cos_k(const float* __restrict__ outb, const float* __restrict__ cf,
                      float* __restrict__ acc){
  const int r = blockIdx.x, tid = threadIdx.x;
  const long rb = (long)r * CLIPC;
  float soc = 0.f, soo = 0.f, scc = 0.f;
#pragma unroll
  for (int k = 0; k < 4; k++){
    const int i = tid + k*256;
    const float o = outb[rb + i], c = cf[rb + i];
    soc += o*c; soo += o*o; scc += c*c;
  }
  for (int off = 32; off; off >>= 1){
    soc += __shfl_xor(soc, off); soo += __shfl_xor(soo, off); scc += __shfl_xor(scc, off);
  }
  __shared__ float r0[4], r1[4], r2[4];
  const int wave = tid >> 6, lane = tid & 63;
  if (lane == 0){ r0[wave] = soc; r1[wave] = soo; r2[wave] = scc; }
  __syncthreads();
  if (tid == 0){
    const float a = r0[0]+r0[1]+r0[2]+r0[3];
    const float b = r1[0]+r1[1]+r1[2]+r1[3];
    const float c = r2[0]+r2[1]+r2[2]+r2[3];
    atomicAdd(acc, a / fmaxf(sqrtf(b*c), 1e-8f));
  }
}

__global__ void fin_k(const float* __restrict__ acc, float* __restrict__ out){
  out[0] = 1.f - acc[0] * (1.f/1152.f);
}

extern "C" void kernel_launch(void* const* d_in, const int* in_sizes, int n_in,
                              void* d_out, int out_size, void* d_ws, size_t ws_size,
                              hipStream_t stream){
  const int*   input_ids = (const int*)  d_in[0];
  const float* images    = (const float*)d_in[1];
  const float* all_feats = (const float*)d_in[2];
  // d_in[3] = patch_hw (unused; always 24)
  const float* norm_gamma = (const float*)d_in[4];
  const float* norm_beta  = (const float*)d_in[5];
  const float* norm_w     = (const float*)d_in[6];
  const float* input_w    = (const float*)d_in[7];
  const float* input_b    = (const float*)d_in[8];
  const float* output_w   = (const float*)d_in[9];
  const float* output_b   = (const float*)d_in[10];
  const float* clip_w     = (const float*)d_in[11];
  const float* clip_b     = (const float*)d_in[12];
  float* out = (float*)d_out;

  // ---- workspace layout (~107 MB) ----
  char* w = (char*)d_ws;
  int*   idxbuf = (int*)w;
  float* acc    = (float*)(w + 64);
  size_t off = 256;
  u16* A_all = (u16*)(w + off); off += 8L*BHW*DD*2;      // 37,748,736
  u16* B_all = (u16*)(w + off); off += 8L*CLIPC*DD*2;    // 33,554,432
  u16* C_all = (u16*)(w + off); off += 8L*BHW*CLIPC*2;   // 18,874,368
  u16* outw  = (u16*)(w + off); off += (long)CLIPC*CLIPC*2;
  u16* clipw = (u16*)(w + off); off += (long)CLIPC*608*2;
  u16* patch = (u16*)(w + off); off += (long)BHW*608*2;
  u16* fuse  = (u16*)(w + off); off += (long)BHW*CLIPC*2;
  float* cf   = (float*)(w + off); off += (long)BHW*CLIPC*4;
  float* outb = (float*)(w + off); off += (long)BHW*CLIPC*4;

  setup_k<<<1, 64, 0, stream>>>(input_ids, idxbuf, acc);
  conv_weights<<<17408, 256, 0, stream>>>(norm_w, input_w, output_w, B_all, outw);
  conv_clipw<<<1024, 128, 0, stream>>>(clip_w, clipw);
  conv_patches<<<1152, 128, 0, stream>>>(images, patch);
  gather_ln<<<dim3(1152, 8), 256, 0, stream>>>(all_feats, idxbuf, norm_gamma, norm_beta, A_all);

  // clip_feats = patches @ clip_w^T + clip_b  (fp32 out)
  gemm_bt<false><<<dim3(9, 8, 1), 256, 0, stream>>>(
      patch, clipw, cf, clip_b, 0, nullptr, CLIPC, 608, 0, 0, 0);

  // batched: slots 0..6 -> vis_j = xn_j @ norm_w[j]^T ; slot 7 -> inp = f24 @ input_w^T + input_b (bf16 out)
  gemm_bt<true><<<dim3(9, 8, 8), 256, 0, stream>>>(
      A_all, B_all, C_all, input_b, 7, nullptr, CLIPC, DD,
      (long)BHW*DD, (long)CLIPC*DD, (long)BHW*CLIPC);

  attn_k<<<dim3(1152, 2), 256, 0, stream>>>(C_all, fuse);

  // out = inp + fuse @ output_w^T + output_b (fp32 out; add = C_all slot 7)
  gemm_bt<false><<<dim3(9, 8, 1), 256, 0, stream>>>(
      fuse, outw, outb, output_b, 0, C_all + 7L*BHW*CLIPC, CLIPC, CLIPC, 0, 0, 0);

  cos_k<<<1152, 256, 0, stream>>>(outb, cf, acc);
  fin_k<<<1, 1, 0, stream>>>(acc, out);
}

// Round 3
// 579.862 us; speedup vs baseline: 1.0998x; 1.0998x over previous
//
#include <hip/hip_runtime.h>

// ---------- problem constants ----------
#define HW_   576
#define BHW   1152      // B*HW
#define DD    2048
#define CLIPC 1024
#define NSEQ  768
#define LL    25
#define KPAD  640       // clip-gemm K (588) padded to a multiple of 64

typedef __bf16 bf16x8 __attribute__((ext_vector_type(8)));
typedef float  f32x4  __attribute__((ext_vector_type(4)));
typedef unsigned short u16;

__device__ __forceinline__ float bf2f(u16 u){
  union { unsigned int i; float f; } v; v.i = ((unsigned int)u) << 16; return v.f;
}
__device__ __forceinline__ u16 f2bf(float f){
  union { float f; unsigned int i; } v; v.f = f;
  unsigned int u = v.i;
  return (u16)((u + 0x7fffu + ((u >> 16) & 1u)) >> 16);  // RNE
}

// async global->LDS, 16B per lane; LDS dest = wave-uniform base + lane*16
__device__ __forceinline__ void gld_lds16(const void* g, void* l){
  __builtin_amdgcn_global_load_lds((__attribute__((address_space(1))) void*)g,
                                   (__attribute__((address_space(3))) void*)l,
                                   16, 0, 0);
}

// ---------- setup: image-token index per sample + zero accumulators ----------
__global__ void setup_k(const int* __restrict__ ids, int* __restrict__ idxbuf,
                        float* __restrict__ rowacc){
  const int lane = threadIdx.x;
  for (int b = 0; b < 2; b++){
    int best = 0x7fffffff;
    for (int i = lane; i < NSEQ; i += 64)
      if (ids[b*NSEQ + i] == -200 && i < best) best = i;
    for (int off = 32; off; off >>= 1){ int o = __shfl_xor(best, off); best = min(best, o); }
    if (lane == 0) idxbuf[b] = best;
  }
  for (int i = lane; i < BHW*4; i += 64) rowacc[i] = 0.f;
}

// ---------- fused prep: weight conv | clipw pad | patchify | gather+LN ----------
// block ranges: [0,17408) conv, [17408,18432) clipw, [18432,19584) patch, [19584,28800) gather_ln
__global__ void prep_k(const float* __restrict__ norm_w, const float* __restrict__ input_w,
                       const float* __restrict__ output_w, const float* __restrict__ clip_w,
                       const float* __restrict__ images, const float* __restrict__ feats,
                       const int* __restrict__ idxbuf,
                       const float* __restrict__ gamma, const float* __restrict__ beta,
                       u16* __restrict__ B_all, u16* __restrict__ outw,
                       u16* __restrict__ clipw, u16* __restrict__ patch,
                       u16* __restrict__ A_all){
  const int blk = blockIdx.x, tid = threadIdx.x;
  if (blk < 17408){
    // fp32 -> bf16: norm_w || input_w -> B_all ; output_w -> outw
    const long n1 = 7L*CLIPC*DD, n2 = (long)CLIPC*DD;
    long idx = ((long)blk*256 + tid) * 4;     // grid covers exactly n1+n2+n3
    const float* s; u16* d;
    if (idx < n1)         { s = norm_w  + idx;              d = B_all + idx; }
    else if (idx < n1+n2) { s = input_w + (idx - n1);       d = B_all + idx; }
    else                  { s = output_w + (idx - n1 - n2); d = outw + (idx - n1 - n2); }
    float4 v = *(const float4*)s;
    union { u16 u[4]; unsigned long long q; } pk;
    pk.u[0] = f2bf(v.x); pk.u[1] = f2bf(v.y); pk.u[2] = f2bf(v.z); pk.u[3] = f2bf(v.w);
    *(unsigned long long*)d = pk.q;
    return;
  }
  if (blk < 18432){
    const int c = blk - 17408;
    for (int k = tid; k < KPAD; k += 256)
      clipw[c*KPAD + k] = (k < 588) ? f2bf(clip_w[c*588 + k]) : (u16)0;
    return;
  }
  if (blk < 19584){
    const int r = blk - 18432;
    const int b = r / HW_, n = r % HW_;
    const int hi = n / 24, wi = n % 24;
    for (int p = tid; p < KPAD; p += 256){
      float v = 0.f;
      if (p < 588){
        int c3 = p / 196, rem = p - c3*196;
        int ph = rem / 14, pw = rem - ph*14;
        v = images[(((long)b*4 + c3)*336 + hi*14 + ph)*336 + wi*14 + pw];
      }
      patch[(long)r*KPAD + p] = f2bf(v);
    }
    return;
  }
  // gather + LayerNorm
  const int q = blk - 19584;
  const int r = q >> 3, g = q & 7;
  const int b = r / HW_, n = r % HW_;
  const int hi = n / 24, wi = n % 24;
  const int tok = idxbuf[b] + 1 + hi*25 + wi;
  const int layer = (g < 7) ? (24 - g*4) : 24;
  const float* src = feats + (((long)(b*NSEQ + tok))*LL + layer)*DD;
  float v[8];
#pragma unroll
  for (int k = 0; k < 8; k++) v[k] = src[tid + k*256];
  u16* dst = A_all + ((long)g*BHW + r)*DD;
  if (g == 7){
#pragma unroll
    for (int k = 0; k < 8; k++) dst[tid + k*256] = f2bf(v[k]);
    return;
  }
  float s = 0.f, qq = 0.f;
#pragma unroll
  for (int k = 0; k < 8; k++){ s += v[k]; qq += v[k]*v[k]; }
  for (int off = 32; off; off >>= 1){ s += __shfl_xor(s, off); qq += __shfl_xor(qq, off); }
  __shared__ float rs[4], rq[4];
  const int wave = tid >> 6, lane = tid & 63;
  if (lane == 0){ rs[wave] = s; rq[wave] = qq; }
  __syncthreads();
  const float ts = rs[0]+rs[1]+rs[2]+rs[3];
  const float tq = rq[0]+rq[1]+rq[2]+rq[3];
  const float mu   = ts * (1.f/2048.f);
  const float var  = tq * (1.f/2048.f) - mu*mu;
  const float rstd = rsqrtf(var + 1e-5f);
  const float* gm = gamma + g*DD;
  const float* bt = beta  + g*DD;
#pragma unroll
  for (int k = 0; k < 8; k++){
    int d = tid + k*256;
    dst[d] = f2bf((v[k]-mu)*rstd*gm[d] + bt[d]);
  }
}

// ---------- GEMM core: 128x128 tile, BK=64, XOR-swizzled LDS, C = A (MxK) * B^T (NxK) ----------
// LDS layout: tile[row][chunk c stored at position c ^ (row&7)], 16B chunks, row stride 128B.
// Staging: lane l fetches global chunk (l&7)^(l>>3) of row (l>>3) -> LDS dest stays base+l*16.
// Fragment reads land at the 8-phase bank minimum (row stride 32 dwords == 0 mod 32, XOR spreads groups).
__device__ __forceinline__ void gemm_core(const u16* __restrict__ Az, const u16* __restrict__ Bz,
                                          int K, int bm, int bn,
                                          u16* __restrict__ As, u16* __restrict__ Bs,
                                          f32x4 (&acc)[4][4]){
  const int tid  = threadIdx.x;
  const int wave = tid >> 6, lane = tid & 63;
  const int l15 = lane & 15, quad = lane >> 4;
  const int wr = (wave >> 1) * 64, wc = (wave & 1) * 64;
  const int laneRow = lane >> 3;
  const int laneCol = (((lane & 7) ^ laneRow) * 8);
  const u16* gA = Az + (long)(bm + wave*32 + laneRow)*K + laneCol;
  const u16* gB = Bz + (long)(bn + wave*32 + laneRow)*K + laneCol;
  u16* lA = &As[wave*2048];
  u16* lB = &Bs[wave*2048];
  const long rs8 = (long)8 * K;

  for (int k0 = 0; k0 < K; k0 += 64){
#pragma unroll
    for (int t = 0; t < 4; t++) gld_lds16(gA + k0 + t*rs8, lA + t*512);
#pragma unroll
    for (int t = 0; t < 4; t++) gld_lds16(gB + k0 + t*rs8, lB + t*512);
    __syncthreads();
#pragma unroll
    for (int s = 0; s < 2; s++){
      bf16x8 af[4], bg[4];
#pragma unroll
      for (int i = 0; i < 4; i++)
        af[i] = *(const bf16x8*)&As[(wr + i*16 + l15)*64 + (((s*4 + quad) ^ (l15 & 7)) * 8)];
#pragma unroll
      for (int j = 0; j < 4; j++)
        bg[j] = *(const bf16x8*)&Bs[(wc + j*16 + l15)*64 + (((s*4 + quad) ^ (l15 & 7)) * 8)];
#pragma unroll
      for (int i = 0; i < 4; i++)
#pragma unroll
        for (int j = 0; j < 4; j++)
          acc[i][j] = __builtin_amdgcn_mfma_f32_16x16x32_bf16(af[i], bg[j], acc[i][j], 0, 0, 0);
    }
    __syncthreads();
  }
}

// ---------- batched GEMM: z=0..6 vis_j, z=7 inp (+input_b), z=8 clip feats (fp32 -> cf, +clip_b) ----------
__global__ __launch_bounds__(256, 3)
void gemm9_k(const u16* __restrict__ A_all, const u16* __restrict__ B_all,
             u16* __restrict__ C_all, const u16* __restrict__ patch,
             const u16* __restrict__ clipw, float* __restrict__ cf,
             const float* __restrict__ input_b, const float* __restrict__ clip_b){
  __shared__ alignas(16) u16 As[128*64];
  __shared__ alignas(16) u16 Bs[128*64];
  const int z = blockIdx.z;
  const int bm = blockIdx.x * 128, bn = blockIdx.y * 128;
  const u16 *Az, *Bz; int K;
  if (z < 8){ Az = A_all + (long)z*BHW*DD; Bz = B_all + (long)z*CLIPC*DD; K = DD; }
  else      { Az = patch; Bz = clipw; K = KPAD; }

  f32x4 acc[4][4] = {};
  gemm_core(Az, Bz, K, bm, bn, As, Bs, acc);

  const int lane = threadIdx.x & 63, wave = threadIdx.x >> 6;
  const int l15 = lane & 15, quad = lane >> 4;
  const int wr = (wave >> 1) * 64, wc = (wave & 1) * 64;

  if (z == 8){
#pragma unroll
    for (int i = 0; i < 4; i++)
#pragma unroll
      for (int j = 0; j < 4; j++)
#pragma unroll
        for (int rr = 0; rr < 4; rr++){
          const int row = bm + wr + i*16 + quad*4 + rr;
          const int col = bn + wc + j*16 + l15;
          cf[(long)row*CLIPC + col] = acc[i][j][rr] + clip_b[col];
        }
  } else {
    u16* C = C_all + (long)z*BHW*CLIPC;
    const bool do_bias = (z == 7);
#pragma unroll
    for (int i = 0; i < 4; i++)
#pragma unroll
      for (int j = 0; j < 4; j++)
#pragma unroll
        for (int rr = 0; rr < 4; rr++){
          const int row = bm + wr + i*16 + quad*4 + rr;
          const int col = bn + wc + j*16 + l15;
          float v = acc[i][j][rr];
          if (do_bias) v += input_b[col];
          C[(long)row*CLIPC + col] = f2bf(v);
        }
  }
}

// ---------- attention: 256 threads = 4 heads ----------
__global__ void attn_k(const u16* __restrict__ C_all, u16* __restrict__ fuse){
  const int r = blockIdx.x;
  const int h = (blockIdx.y << 2) | (threadIdx.x >> 6);
  const int lane = threadIdx.x & 63;
  const long slot = (long)BHW * CLIPC;
  const long rb = (long)r * CLIPC;
  const int c0 = h*128 + lane, c1 = c0 + 64;
  const float q0 = bf2f(C_all[rb + c0]), q1 = bf2f(C_all[rb + c1]);
  float k0v[6], k1v[6], dt[6];
#pragma unroll
  for (int t = 0; t < 6; t++){
    const u16* base = C_all + (long)(t+1)*slot + rb;
    k0v[t] = bf2f(base[c0]); k1v[t] = bf2f(base[c1]);
    dt[t] = q0*k0v[t] + q1*k1v[t];
  }
#pragma unroll
  for (int t = 0; t < 6; t++)
    for (int off = 32; off; off >>= 1) dt[t] += __shfl_xor(dt[t], off);
  float l[6], e[6];
#pragma unroll
  for (int t = 0; t < 6; t++) l[t] = dt[t] * 0.03125f;
  float m = l[0];
#pragma unroll
  for (int t = 1; t < 6; t++) m = fmaxf(m, l[t]);
  float ssum = 0.f;
#pragma unroll
  for (int t = 0; t < 6; t++){ e[t] = __expf(l[t] - m); ssum += e[t]; }
  const float inv = 1.f / ssum;
  float f0 = 0.f, f1 = 0.f;
#pragma unroll
  for (int t = 0; t < 6; t++){ const float a = e[t]*inv; f0 += a*k0v[t]; f1 += a*k1v[t]; }
  fuse[rb + c0] = f2bf(f0);
  fuse[rb + c1] = f2bf(f1);
}

// ---------- output GEMM + fused cosine partials ----------
// out = inp + fuse @ output_w^T + output_b ; accumulate per-row {o.c, o.o, c.c} into rowacc
__global__ __launch_bounds__(256, 3)
void gemm_out_k(const u16* __restrict__ fuse, const u16* __restrict__ outw,
                const u16* __restrict__ inp, const float* __restrict__ output_b,
                const float* __restrict__ cf, float* __restrict__ rowacc){
  __shared__ alignas(16) u16 As[128*64];
  __shared__ alignas(16) u16 Bs[128*64];
  const int bm = blockIdx.x * 128, bn = blockIdx.y * 128;
  f32x4 acc[4][4] = {};
  gemm_core(fuse, outw, CLIPC, bm, bn, As, Bs, acc);

  const int lane = threadIdx.x & 63, wave = threadIdx.x >> 6;
  const int l15 = lane & 15, quad = lane >> 4;
  const int wr = (wave >> 1) * 64, wc = (wave & 1) * 64;

#pragma unroll
  for (int i = 0; i < 4; i++)
#pragma unroll
    for (int rr = 0; rr < 4; rr++){
      const int row = bm + wr + i*16 + quad*4 + rr;
      float soc = 0.f, soo = 0.f, scc = 0.f;
#pragma unroll
      for (int j = 0; j < 4; j++){
        const int col = bn + wc + j*16 + l15;
        const long p = (long)row*CLIPC + col;
        const float o = acc[i][j][rr] + output_b[col] + bf2f(inp[p]);
        const float c = cf[p];
        soc += o*c; soo += o*o; scc += c*c;
      }
#pragma unroll
      for (int off = 1; off < 16; off <<= 1){
        soc += __shfl_xor(soc, off); soo += __shfl_xor(soo, off); scc += __shfl_xor(scc, off);
      }
      if (l15 == 0){
        atomicAdd(&rowacc[row*4 + 0], soc);
        atomicAdd(&rowacc[row*4 + 1], soo);
        atomicAdd(&rowacc[row*4 + 2], scc);
      }
    }
}

// ---------- final: mean cosine -> loss ----------
__global__ void fin_k(const float* __restrict__ rowacc, float* __restrict__ out){
  const int tid = threadIdx.x;
  float s = 0.f;
  for (int r = tid; r < BHW; r += 256){
    const float soc = rowacc[r*4], soo = rowacc[r*4+1], scc = rowacc[r*4+2];
    s += soc / fmaxf(sqrtf(soo*scc), 1e-8f);
  }
  for (int off = 32; off; off >>= 1) s += __shfl_xor(s, off);
  __shared__ float rs[4];
  const int wave = tid >> 6, lane = tid & 63;
  if (lane == 0) rs[wave] = s;
  __syncthreads();
  if (tid == 0) out[0] = 1.f - (rs[0]+rs[1]+rs[2]+rs[3]) * (1.f/(float)BHW);
}

extern "C" void kernel_launch(void* const* d_in, const int* in_sizes, int n_in,
                              void* d_out, int out_size, void* d_ws, size_t ws_size,
                              hipStream_t stream){
  const int*   input_ids = (const int*)  d_in[0];
  const float* images    = (const float*)d_in[1];
  const float* all_feats = (const float*)d_in[2];
  const float* norm_gamma = (const float*)d_in[4];
  const float* norm_beta  = (const float*)d_in[5];
  const float* norm_w     = (const float*)d_in[6];
  const float* input_w    = (const float*)d_in[7];
  const float* input_b    = (const float*)d_in[8];
  const float* output_w   = (const float*)d_in[9];
  const float* output_b   = (const float*)d_in[10];
  const float* clip_w     = (const float*)d_in[11];
  const float* clip_b     = (const float*)d_in[12];
  float* out = (float*)d_out;

  // ---- workspace layout (~102 MB) ----
  char* w = (char*)d_ws;
  int*   idxbuf = (int*)w;
  size_t off = 256;
  u16* A_all = (u16*)(w + off); off += 8L*BHW*DD*2;
  u16* B_all = (u16*)(w + off); off += 8L*CLIPC*DD*2;
  u16* C_all = (u16*)(w + off); off += 8L*BHW*CLIPC*2;
  u16* outw  = (u16*)(w + off); off += (long)CLIPC*CLIPC*2;
  u16* clipw = (u16*)(w + off); off += (long)CLIPC*KPAD*2;
  u16* patch = (u16*)(w + off); off += (long)BHW*KPAD*2;
  u16* fuse  = (u16*)(w + off); off += (long)BHW*CLIPC*2;
  float* cf     = (float*)(w + off); off += (long)BHW*CLIPC*4;
  float* rowacc = (float*)(w + off); off += (long)BHW*4*4;

  setup_k<<<1, 64, 0, stream>>>(input_ids, idxbuf, rowacc);
  prep_k<<<28800, 256, 0, stream>>>(norm_w, input_w, output_w, clip_w, images, all_feats,
                                    idxbuf, norm_gamma, norm_beta,
                                    B_all, outw, clipw, patch, A_all);
  gemm9_k<<<dim3(9, 8, 9), 256, 0, stream>>>(A_all, B_all, C_all, patch, clipw, cf,
                                             input_b, clip_b);
  attn_k<<<dim3(1152, 2), 256, 0, stream>>>(C_all, fuse);
  gemm_out_k<<<dim3(9, 8), 256, 0, stream>>>(fuse, outw, C_all + 7L*BHW*CLIPC,
                                             output_b, cf, rowacc);
  fin_k<<<1, 256, 0, stream>>>(rowacc, out);
}

// Round 4
// 554.702 us; speedup vs baseline: 1.1496x; 1.0454x over previous
//
#include <hip/hip_runtime.h>

// ---------- problem constants ----------
#define HW_   576
#define BHW   1152      // B*HW
#define DD    2048
#define CLIPC 1024
#define NSEQ  768
#define LL    25
#define KPAD  640       // clip-gemm K (588) padded to a multiple of 64

// fp8 pre-scaling: A stored as 8*x, B stored as 32*w  ->  acc = 256 * true
#define ASCALE 8.0f
#define BSCALE 32.0f
#define INV_AB (1.0f/256.0f)

typedef __bf16 bf16x8 __attribute__((ext_vector_type(8)));
typedef float  f32x4  __attribute__((ext_vector_type(4)));
typedef int    i32x8  __attribute__((ext_vector_type(8)));
typedef unsigned short u16;
typedef unsigned char  u8;

__device__ __forceinline__ float bf2f(u16 u){
  union { unsigned int i; float f; } v; v.i = ((unsigned int)u) << 16; return v.f;
}
__device__ __forceinline__ u16 f2bf(float f){
  union { float f; unsigned int i; } v; v.f = f;
  unsigned int u = v.i;
  return (u16)((u + 0x7fffu + ((u >> 16) & 1u)) >> 16);  // RNE
}
__device__ __forceinline__ unsigned int pk2bf(float a, float b){
  return ((unsigned int)f2bf(a)) | (((unsigned int)f2bf(b)) << 16);
}
__device__ __forceinline__ unsigned int pk4_fp8(float a, float b, float c, float d){
  int v = 0;
  v = __builtin_amdgcn_cvt_pk_fp8_f32(a, b, v, false);
  v = __builtin_amdgcn_cvt_pk_fp8_f32(c, d, v, true);
  return (unsigned int)v;
}

// async global->LDS, 16B per lane; LDS dest = wave-uniform base + lane*16
__device__ __forceinline__ void gld_lds16(const void* g, void* l){
  __builtin_amdgcn_global_load_lds((__attribute__((address_space(1))) void*)g,
                                   (__attribute__((address_space(3))) void*)l,
                                   16, 0, 0);
}

// ---------- setup ----------
__global__ void setup_k(const int* __restrict__ ids, int* __restrict__ idxbuf,
                        float* __restrict__ rowacc){
  const int lane = threadIdx.x;
  for (int b = 0; b < 2; b++){
    int best = 0x7fffffff;
    for (int i = lane; i < NSEQ; i += 64)
      if (ids[b*NSEQ + i] == -200 && i < best) best = i;
    for (int off = 32; off; off >>= 1){ int o = __shfl_xor(best, off); best = min(best, o); }
    if (lane == 0) idxbuf[b] = best;
  }
  for (int i = lane; i < BHW*4; i += 64) rowacc[i] = 0.f;
}

// ---------- fused prep ----------
// [0,7168): norm_w -> fp8 x32 (B8)      [7168,8192): input_w -> bf16 (inpw)
// [8192,8704): output_w -> bf16 (outw)  [8704,9728): clipw pad
// [9728,10880): patchify               [10880,20096): gather+LN (g<7 fp8 x8, g==7 bf16)
__global__ void prep_k(const float* __restrict__ norm_w, const float* __restrict__ input_w,
                       const float* __restrict__ output_w, const float* __restrict__ clip_w,
                       const float* __restrict__ images, const float* __restrict__ feats,
                       const int* __restrict__ idxbuf,
                       const float* __restrict__ gamma, const float* __restrict__ beta,
                       u8* __restrict__ B8, u16* __restrict__ inpw, u16* __restrict__ outw,
                       u16* __restrict__ clipw, u16* __restrict__ patch,
                       u8* __restrict__ A8, u16* __restrict__ A7){
  const int blk = blockIdx.x, tid = threadIdx.x;
  if (blk < 7168){
    long idx = (long)blk*2048 + tid*8;
    float4 v0 = *(const float4*)(norm_w + idx);
    float4 v1 = *(const float4*)(norm_w + idx + 4);
    uint2 o;
    o.x = pk4_fp8(v0.x*BSCALE, v0.y*BSCALE, v0.z*BSCALE, v0.w*BSCALE);
    o.y = pk4_fp8(v1.x*BSCALE, v1.y*BSCALE, v1.z*BSCALE, v1.w*BSCALE);
    *(uint2*)(B8 + idx) = o;
    return;
  }
  if (blk < 8704){
    const bool isInp = (blk < 8192);
    long idx = (long)(blk - (isInp ? 7168 : 8192))*2048 + tid*8;
    const float* s = isInp ? (input_w + idx) : (output_w + idx);
    float4 v0 = *(const float4*)s;
    float4 v1 = *(const float4*)(s + 4);
    uint4 o = { pk2bf(v0.x,v0.y), pk2bf(v0.z,v0.w), pk2bf(v1.x,v1.y), pk2bf(v1.z,v1.w) };
    *(uint4*)((isInp ? inpw : outw) + idx) = o;
    return;
  }
  if (blk < 9728){
    const int c = blk - 8704;
    for (int k = tid; k < KPAD; k += 256)
      clipw[c*KPAD + k] = (k < 588) ? f2bf(clip_w[c*588 + k]) : (u16)0;
    return;
  }
  if (blk < 10880){
    const int r = blk - 9728;
    const int b = r / HW_, n = r % HW_;
    const int hi = n / 24, wi = n % 24;
    for (int p = tid; p < KPAD; p += 256){
      float v = 0.f;
      if (p < 588){
        int c3 = p / 196, rem = p - c3*196;
        int ph = rem / 14, pw = rem - ph*14;
        v = images[(((long)b*4 + c3)*336 + hi*14 + ph)*336 + wi*14 + pw];
      }
      patch[(long)r*KPAD + p] = f2bf(v);
    }
    return;
  }
  // gather + LayerNorm
  const int q = blk - 10880;
  const int r = q >> 3, g = q & 7;
  const int b = r / HW_, n = r % HW_;
  const int hi = n / 24, wi = n % 24;
  const int tok = idxbuf[b] + 1 + hi*25 + wi;
  const int layer = (g < 7) ? (24 - g*4) : 24;
  const float* src = feats + (((long)(b*NSEQ + tok))*LL + layer)*DD + tid*8;
  float4 a = *(const float4*)src;
  float4 c = *(const float4*)(src + 4);
  if (g == 7){
    uint4 o = { pk2bf(a.x,a.y), pk2bf(a.z,a.w), pk2bf(c.x,c.y), pk2bf(c.z,c.w) };
    *(uint4*)(A7 + (long)r*DD + tid*8) = o;
    return;
  }
  float s  = a.x+a.y+a.z+a.w + c.x+c.y+c.z+c.w;
  float qq = a.x*a.x+a.y*a.y+a.z*a.z+a.w*a.w + c.x*c.x+c.y*c.y+c.z*c.z+c.w*c.w;
  for (int off = 32; off; off >>= 1){ s += __shfl_xor(s, off); qq += __shfl_xor(qq, off); }
  __shared__ float rs[4], rq[4];
  const int wave = tid >> 6, lane = tid & 63;
  if (lane == 0){ rs[wave] = s; rq[wave] = qq; }
  __syncthreads();
  const float ts = rs[0]+rs[1]+rs[2]+rs[3];
  const float tq = rq[0]+rq[1]+rq[2]+rq[3];
  const float mu   = ts * (1.f/2048.f);
  const float var  = tq * (1.f/2048.f) - mu*mu;
  const float rstd = rsqrtf(var + 1e-5f);
  const float4 g0 = *(const float4*)(gamma + g*DD + tid*8);
  const float4 g1 = *(const float4*)(gamma + g*DD + tid*8 + 4);
  const float4 b0 = *(const float4*)(beta  + g*DD + tid*8);
  const float4 b1 = *(const float4*)(beta  + g*DD + tid*8 + 4);
  uint2 o;
  o.x = pk4_fp8(((a.x-mu)*rstd*g0.x + b0.x)*ASCALE, ((a.y-mu)*rstd*g0.y + b0.y)*ASCALE,
                ((a.z-mu)*rstd*g0.z + b0.z)*ASCALE, ((a.w-mu)*rstd*g0.w + b0.w)*ASCALE);
  o.y = pk4_fp8(((c.x-mu)*rstd*g1.x + b1.x)*ASCALE, ((c.y-mu)*rstd*g1.y + b1.y)*ASCALE,
                ((c.z-mu)*rstd*g1.z + b1.z)*ASCALE, ((c.w-mu)*rstd*g1.w + b1.w)*ASCALE);
  *(uint2*)(A8 + ((long)g*BHW + r)*DD + tid*8) = o;
}

// ---------- MX-fp8 batched GEMM: slots 0..6, C = (A8[z] * B8[z]^T) * 1/256 -> bf16 vis ----------
// 128x128 tile, BK=128 fp8 (16 KB/matrix), XOR-16B-chunk swizzled LDS, identity E8M0 scales.
__global__ __launch_bounds__(256, 3)
void gemm_fp8_k(const u8* __restrict__ A_all, const u8* __restrict__ B_all,
                u16* __restrict__ C_all){
  __shared__ alignas(16) u8 As[128*128];
  __shared__ alignas(16) u8 Bs[128*128];
  const int z = blockIdx.z;
  const u8* Az = A_all + (long)z*BHW*DD;
  const u8* Bz = B_all + (long)z*CLIPC*DD;
  const int bm = blockIdx.x*128, bn = blockIdx.y*128;
  const int tid = threadIdx.x, wave = tid >> 6, lane = tid & 63;
  const int l15 = lane & 15, quad = lane >> 4;
  const int wr = (wave >> 1)*64, wc = (wave & 1)*64;
  f32x4 acc[4][4] = {};

  // staging: wave stages rows [wave*32, +32); 8 rows/inst; chunk c of row r at LDS pos c^(r&7)
  const int laneRow   = lane >> 3;
  const int laneChunk = (lane & 7) ^ laneRow;
  const u8* gA = Az + (long)(bm + wave*32 + laneRow)*DD + laneChunk*16;
  const u8* gB = Bz + (long)(bn + wave*32 + laneRow)*DD + laneChunk*16;
  u8* lA = &As[wave*32*128];
  u8* lB = &Bs[wave*32*128];
  const long rs8 = 8L*DD;

  for (int k0 = 0; k0 < DD; k0 += 128){
#pragma unroll
    for (int t = 0; t < 4; t++) gld_lds16(gA + k0 + t*rs8, lA + t*1024);
#pragma unroll
    for (int t = 0; t < 4; t++) gld_lds16(gB + k0 + t*rs8, lB + t*1024);
    __syncthreads();
    i32x8 af[4], bg[4];
    const int sw = l15 & 7;
#pragma unroll
    for (int i = 0; i < 4; i++){
      const u8* rp = &As[(wr + i*16 + l15)*128];
      uint4 lo = *(const uint4*)(rp + (((quad*2 + 0) ^ sw)*16));
      uint4 hi = *(const uint4*)(rp + (((quad*2 + 1) ^ sw)*16));
      af[i] = (i32x8){(int)lo.x,(int)lo.y,(int)lo.z,(int)lo.w,
                      (int)hi.x,(int)hi.y,(int)hi.z,(int)hi.w};
    }
#pragma unroll
    for (int j = 0; j < 4; j++){
      const u8* rp = &Bs[(wc + j*16 + l15)*128];
      uint4 lo = *(const uint4*)(rp + (((quad*2 + 0) ^ sw)*16));
      uint4 hi = *(const uint4*)(rp + (((quad*2 + 1) ^ sw)*16));
      bg[j] = (i32x8){(int)lo.x,(int)lo.y,(int)lo.z,(int)lo.w,
                      (int)hi.x,(int)hi.y,(int)hi.z,(int)hi.w};
    }
#pragma unroll
    for (int i = 0; i < 4; i++)
#pragma unroll
      for (int j = 0; j < 4; j++)
        acc[i][j] = __builtin_amdgcn_mfma_scale_f32_16x16x128_f8f6f4(
            af[i], bg[j], acc[i][j], 0, 0, 0, 0x7F7F7F7F, 0, 0x7F7F7F7F);
    __syncthreads();
  }

  u16* C = C_all + (long)z*BHW*CLIPC;
#pragma unroll
  for (int i = 0; i < 4; i++)
#pragma unroll
    for (int j = 0; j < 4; j++)
#pragma unroll
      for (int rr = 0; rr < 4; rr++){
        const int row = bm + wr + i*16 + quad*4 + rr;
        const int col = bn + wc + j*16 + l15;
        C[(long)row*CLIPC + col] = f2bf(acc[i][j][rr] * INV_AB);
      }
}

// ---------- bf16 GEMM core (BK=64, XOR swizzle) ----------
__device__ __forceinline__ void gemm_core(const u16* __restrict__ Az, const u16* __restrict__ Bz,
                                          int K, int bm, int bn,
                                          u16* __restrict__ As, u16* __restrict__ Bs,
                                          f32x4 (&acc)[4][4]){
  const int tid  = threadIdx.x;
  const int wave = tid >> 6, lane = tid & 63;
  const int l15 = lane & 15, quad = lane >> 4;
  const int wr = (wave >> 1) * 64, wc = (wave & 1) * 64;
  const int laneRow = lane >> 3;
  const int laneCol = (((lane & 7) ^ laneRow) * 8);
  const u16* gA = Az + (long)(bm + wave*32 + laneRow)*K + laneCol;
  const u16* gB = Bz + (long)(bn + wave*32 + laneRow)*K + laneCol;
  u16* lA = &As[wave*2048];
  u16* lB = &Bs[wave*2048];
  const long rs8 = (long)8 * K;

  for (int k0 = 0; k0 < K; k0 += 64){
#pragma unroll
    for (int t = 0; t < 4; t++) gld_lds16(gA + k0 + t*rs8, lA + t*512);
#pragma unroll
    for (int t = 0; t < 4; t++) gld_lds16(gB + k0 + t*rs8, lB + t*512);
    __syncthreads();
#pragma unroll
    for (int s = 0; s < 2; s++){
      bf16x8 af[4], bg[4];
#pragma unroll
      for (int i = 0; i < 4; i++)
        af[i] = *(const bf16x8*)&As[(wr + i*16 + l15)*64 + (((s*4 + quad) ^ (l15 & 7)) * 8)];
#pragma unroll
      for (int j = 0; j < 4; j++)
        bg[j] = *(const bf16x8*)&Bs[(wc + j*16 + l15)*64 + (((s*4 + quad) ^ (l15 & 7)) * 8)];
#pragma unroll
      for (int i = 0; i < 4; i++)
#pragma unroll
        for (int j = 0; j < 4; j++)
          acc[i][j] = __builtin_amdgcn_mfma_f32_16x16x32_bf16(af[i], bg[j], acc[i][j], 0, 0, 0);
    }
    __syncthreads();
  }
}

// ---------- bf16 misc GEMM: z=0 clip feats (fp32 -> cf, +clip_b); z=1 inp (bf16 -> C7, +input_b) ----------
__global__ __launch_bounds__(256, 3)
void gemm_misc_k(const u16* __restrict__ patch, const u16* __restrict__ clipw,
                 const u16* __restrict__ A7, const u16* __restrict__ inpw,
                 float* __restrict__ cf, u16* __restrict__ C7,
                 const float* __restrict__ clip_b, const float* __restrict__ input_b){
  __shared__ alignas(16) u16 As[128*64];
  __shared__ alignas(16) u16 Bs[128*64];
  const int z = blockIdx.z;
  const int bm = blockIdx.x*128, bn = blockIdx.y*128;
  const u16* Az = z ? A7 : patch;
  const u16* Bz = z ? inpw : clipw;
  const int K = z ? DD : KPAD;
  f32x4 acc[4][4] = {};
  gemm_core(Az, Bz, K, bm, bn, As, Bs, acc);

  const int lane = threadIdx.x & 63, wave = threadIdx.x >> 6;
  const int l15 = lane & 15, quad = lane >> 4;
  const int wr = (wave >> 1)*64, wc = (wave & 1)*64;
#pragma unroll
  for (int i = 0; i < 4; i++)
#pragma unroll
    for (int j = 0; j < 4; j++)
#pragma unroll
      for (int rr = 0; rr < 4; rr++){
        const int row = bm + wr + i*16 + quad*4 + rr;
        const int col = bn + wc + j*16 + l15;
        if (z) C7[(long)row*CLIPC + col] = f2bf(acc[i][j][rr] + input_b[col]);
        else   cf[(long)row*CLIPC + col] = acc[i][j][rr] + clip_b[col];
      }
}

// ---------- attention: 256 threads = 4 heads ----------
__global__ void attn_k(const u16* __restrict__ C_all, u16* __restrict__ fuse){
  const int r = blockIdx.x;
  const int h = (blockIdx.y << 2) | (threadIdx.x >> 6);
  const int lane = threadIdx.x & 63;
  const long slot = (long)BHW * CLIPC;
  const long rb = (long)r * CLIPC;
  const int c0 = h*128 + lane, c1 = c0 + 64;
  const float q0 = bf2f(C_all[rb + c0]), q1 = bf2f(C_all[rb + c1]);
  float k0v[6], k1v[6], dt[6];
#pragma unroll
  for (int t = 0; t < 6; t++){
    const u16* base = C_all + (long)(t+1)*slot + rb;
    k0v[t] = bf2f(base[c0]); k1v[t] = bf2f(base[c1]);
    dt[t] = q0*k0v[t] + q1*k1v[t];
  }
#pragma unroll
  for (int t = 0; t < 6; t++)
    for (int off = 32; off; off >>= 1) dt[t] += __shfl_xor(dt[t], off);
  float l[6], e[6];
#pragma unroll
  for (int t = 0; t < 6; t++) l[t] = dt[t] * 0.03125f;
  float m = l[0];
#pragma unroll
  for (int t = 1; t < 6; t++) m = fmaxf(m, l[t]);
  float ssum = 0.f;
#pragma unroll
  for (int t = 0; t < 6; t++){ e[t] = __expf(l[t] - m); ssum += e[t]; }
  const float inv = 1.f / ssum;
  float f0 = 0.f, f1 = 0.f;
#pragma unroll
  for (int t = 0; t < 6; t++){ const float a = e[t]*inv; f0 += a*k0v[t]; f1 += a*k1v[t]; }
  fuse[rb + c0] = f2bf(f0);
  fuse[rb + c1] = f2bf(f1);
}

// ---------- output GEMM + fused cosine partials ----------
__global__ __launch_bounds__(256, 3)
void gemm_out_k(const u16* __restrict__ fuse, const u16* __restrict__ outw,
                const u16* __restrict__ inp, const float* __restrict__ output_b,
                const float* __restrict__ cf, float* __restrict__ rowacc){
  __shared__ alignas(16) u16 As[128*64];
  __shared__ alignas(16) u16 Bs[128*64];
  const int bm = blockIdx.x*128, bn = blockIdx.y*128;
  f32x4 acc[4][4] = {};
  gemm_core(fuse, outw, CLIPC, bm, bn, As, Bs, acc);

  const int lane = threadIdx.x & 63, wave = threadIdx.x >> 6;
  const int l15 = lane & 15, quad = lane >> 4;
  const int wr = (wave >> 1)*64, wc = (wave & 1)*64;
#pragma unroll
  for (int i = 0; i < 4; i++)
#pragma unroll
    for (int rr = 0; rr < 4; rr++){
      const int row = bm + wr + i*16 + quad*4 + rr;
      float soc = 0.f, soo = 0.f, scc = 0.f;
#pragma unroll
      for (int j = 0; j < 4; j++){
        const int col = bn + wc + j*16 + l15;
        const long p = (long)row*CLIPC + col;
        const float o = acc[i][j][rr] + output_b[col] + bf2f(inp[p]);
        const float c = cf[p];
        soc += o*c; soo += o*o; scc += c*c;
      }
#pragma unroll
      for (int off = 1; off < 16; off <<= 1){
        soc += __shfl_xor(soc, off); soo += __shfl_xor(soo, off); scc += __shfl_xor(scc, off);
      }
      if (l15 == 0){
        atomicAdd(&rowacc[row*4 + 0], soc);
        atomicAdd(&rowacc[row*4 + 1], soo);
        atomicAdd(&rowacc[row*4 + 2], scc);
      }
    }
}

// ---------- final ----------
__global__ void fin_k(const float* __restrict__ rowacc, float* __restrict__ out){
  const int tid = threadIdx.x;
  float s = 0.f;
  for (int r = tid; r < BHW; r += 256){
    const float soc = rowacc[r*4], soo = rowacc[r*4+1], scc = rowacc[r*4+2];
    s += soc / fmaxf(sqrtf(soo*scc), 1e-8f);
  }
  for (int off = 32; off; off >>= 1) s += __shfl_xor(s, off);
  __shared__ float rs[4];
  const int wave = tid >> 6, lane = tid & 63;
  if (lane == 0) rs[wave] = s;
  __syncthreads();
  if (tid == 0) out[0] = 1.f - (rs[0]+rs[1]+rs[2]+rs[3]) * (1.f/(float)BHW);
}

extern "C" void kernel_launch(void* const* d_in, const int* in_sizes, int n_in,
                              void* d_out, int out_size, void* d_ws, size_t ws_size,
                              hipStream_t stream){
  const int*   input_ids = (const int*)  d_in[0];
  const float* images    = (const float*)d_in[1];
  const float* all_feats = (const float*)d_in[2];
  const float* norm_gamma = (const float*)d_in[4];
  const float* norm_beta  = (const float*)d_in[5];
  const float* norm_w     = (const float*)d_in[6];
  const float* input_w    = (const float*)d_in[7];
  const float* input_b    = (const float*)d_in[8];
  const float* output_w   = (const float*)d_in[9];
  const float* output_b   = (const float*)d_in[10];
  const float* clip_w     = (const float*)d_in[11];
  const float* clip_b     = (const float*)d_in[12];
  float* out = (float*)d_out;

  // ---- workspace layout (~75 MB) ----
  char* w = (char*)d_ws;
  int*   idxbuf = (int*)w;
  size_t off = 256;
  u8*  A8    = (u8*) (w + off); off += 7L*BHW*DD;          // 16.5 MB fp8 (x8)
  u16* A7    = (u16*)(w + off); off += (long)BHW*DD*2;     // 4.7 MB bf16
  u8*  B8    = (u8*) (w + off); off += 7L*CLIPC*DD;        // 14.7 MB fp8 (x32)
  u16* inpw  = (u16*)(w + off); off += (long)CLIPC*DD*2;   // 4.2 MB
  u16* outw  = (u16*)(w + off); off += (long)CLIPC*CLIPC*2;
  u16* clipw = (u16*)(w + off); off += (long)CLIPC*KPAD*2;
  u16* patch = (u16*)(w + off); off += (long)BHW*KPAD*2;
  u16* C_all = (u16*)(w + off); off += 8L*BHW*CLIPC*2;     // slots 0..6 vis, slot 7 inp
  u16* fuse  = (u16*)(w + off); off += (long)BHW*CLIPC*2;
  float* cf     = (float*)(w + off); off += (long)BHW*CLIPC*4;
  float* rowacc = (float*)(w + off); off += (long)BHW*4*4;

  setup_k<<<1, 64, 0, stream>>>(input_ids, idxbuf, rowacc);
  prep_k<<<20096, 256, 0, stream>>>(norm_w, input_w, output_w, clip_w, images, all_feats,
                                    idxbuf, norm_gamma, norm_beta,
                                    B8, inpw, outw, clipw, patch, A8, A7);
  gemm_fp8_k<<<dim3(9, 8, 7), 256, 0, stream>>>(A8, B8, C_all);
  gemm_misc_k<<<dim3(9, 8, 2), 256, 0, stream>>>(patch, clipw, A7, inpw, cf,
                                                 C_all + 7L*BHW*CLIPC, clip_b, input_b);
  attn_k<<<dim3(1152, 2), 256, 0, stream>>>(C_all, fuse);
  gemm_out_k<<<dim3(9, 8), 256, 0, stream>>>(fuse, outw, C_all + 7L*BHW*CLIPC,
                                             output_b, cf, rowacc);
  fin_k<<<1, 256, 0, stream>>>(rowacc, out);
}

// Round 5
// 531.913 us; speedup vs baseline: 1.1989x; 1.0428x over previous
//
#include <hip/hip_runtime.h>

// ---------- problem constants ----------
#define HW_   576
#define BHW   1152      // B*HW
#define DD    2048
#define CLIPC 1024
#define NSEQ  768
#define LL    25
#define KPAD  640       // clip-gemm K (588) padded to a multiple of 64

// fp8 pre-scaling: A stored as 8*x, B stored as 32*w  ->  acc = 256 * true
#define ASCALE 8.0f
#define BSCALE 32.0f
#define INV_AB (1.0f/256.0f)

typedef __bf16 bf16x8 __attribute__((ext_vector_type(8)));
typedef float  f32x4  __attribute__((ext_vector_type(4)));
typedef int    i32x8  __attribute__((ext_vector_type(8)));
typedef unsigned short u16;
typedef unsigned char  u8;

__device__ __forceinline__ float bf2f(u16 u){
  union { unsigned int i; float f; } v; v.i = ((unsigned int)u) << 16; return v.f;
}
__device__ __forceinline__ u16 f2bf(float f){
  union { float f; unsigned int i; } v; v.f = f;
  unsigned int u = v.i;
  return (u16)((u + 0x7fffu + ((u >> 16) & 1u)) >> 16);  // RNE
}
__device__ __forceinline__ unsigned int pk2bf(float a, float b){
  return ((unsigned int)f2bf(a)) | (((unsigned int)f2bf(b)) << 16);
}
__device__ __forceinline__ unsigned int pk4_fp8(float a, float b, float c, float d){
  int v = 0;
  v = __builtin_amdgcn_cvt_pk_fp8_f32(a, b, v, false);
  v = __builtin_amdgcn_cvt_pk_fp8_f32(c, d, v, true);
  return (unsigned int)v;
}

// async global->LDS, 16B per lane; LDS dest = wave-uniform base + lane*16
__device__ __forceinline__ void gld_lds16(const void* g, void* l){
  __builtin_amdgcn_global_load_lds((__attribute__((address_space(1))) void*)g,
                                   (__attribute__((address_space(3))) void*)l,
                                   16, 0, 0);
}

// ---------- fused prep (launch 1 of 4) ----------
// [0,7168): norm_w -> fp8 x32 (B8)      [7168,8192): input_w -> bf16 (inpw)
// [8192,8704): output_w -> bf16 (outw)  [8704,9728): clipw pad (+blk8704: zero rowacc/counter)
// [9728,10880): patchify               [10880,20096): gather+LN (idx computed inline)
__global__ void prep_k(const float* __restrict__ norm_w, const float* __restrict__ input_w,
                       const float* __restrict__ output_w, const float* __restrict__ clip_w,
                       const float* __restrict__ images, const float* __restrict__ feats,
                       const int* __restrict__ ids,
                       const float* __restrict__ gamma, const float* __restrict__ beta,
                       u8* __restrict__ B8, u16* __restrict__ inpw, u16* __restrict__ outw,
                       u16* __restrict__ clipw, u16* __restrict__ patch,
                       u8* __restrict__ A8, u16* __restrict__ A7,
                       float* __restrict__ rowacc, unsigned int* __restrict__ done){
  const int blk = blockIdx.x, tid = threadIdx.x;
  if (blk < 7168){
    long idx = (long)blk*2048 + tid*8;
    float4 v0 = *(const float4*)(norm_w + idx);
    float4 v1 = *(const float4*)(norm_w + idx + 4);
    uint2 o;
    o.x = pk4_fp8(v0.x*BSCALE, v0.y*BSCALE, v0.z*BSCALE, v0.w*BSCALE);
    o.y = pk4_fp8(v1.x*BSCALE, v1.y*BSCALE, v1.z*BSCALE, v1.w*BSCALE);
    *(uint2*)(B8 + idx) = o;
    return;
  }
  if (blk < 8704){
    const bool isInp = (blk < 8192);
    long idx = (long)(blk - (isInp ? 7168 : 8192))*2048 + tid*8;
    const float* s = isInp ? (input_w + idx) : (output_w + idx);
    float4 v0 = *(const float4*)s;
    float4 v1 = *(const float4*)(s + 4);
    uint4 o = { pk2bf(v0.x,v0.y), pk2bf(v0.z,v0.w), pk2bf(v1.x,v1.y), pk2bf(v1.z,v1.w) };
    *(uint4*)((isInp ? inpw : outw) + idx) = o;
    return;
  }
  if (blk < 9728){
    const int c = blk - 8704;
    for (int k = tid; k < KPAD; k += 256)
      clipw[c*KPAD + k] = (k < 588) ? f2bf(clip_w[c*588 + k]) : (u16)0;
    if (blk == 8704){
      for (int i = tid; i < BHW*4; i += 256) rowacc[i] = 0.f;
      if (tid == 0) *done = 0u;
    }
    return;
  }
  if (blk < 10880){
    const int r = blk - 9728;
    const int b = r / HW_, n = r % HW_;
    const int hi = n / 24, wi = n % 24;
    for (int p = tid; p < KPAD; p += 256){
      float v = 0.f;
      if (p < 588){
        int c3 = p / 196, rem = p - c3*196;
        int ph = rem / 14, pw = rem - ph*14;
        v = images[(((long)b*4 + c3)*336 + hi*14 + ph)*336 + wi*14 + pw];
      }
      patch[(long)r*KPAD + p] = f2bf(v);
    }
    return;
  }
  // gather + LayerNorm (image-token index computed inline; ids rows are L2-resident)
  const int q = blk - 10880;
  const int r = q >> 3, g = q & 7;
  const int b = r / HW_, n = r % HW_;
  const int hi = n / 24, wi = n % 24;
  __shared__ int ridx[4];
  __shared__ float rs[4], rq[4];
  {
    int best = 0x7fffffff;
    for (int i = tid; i < NSEQ; i += 256)
      if (ids[b*NSEQ + i] == -200 && i < best) best = i;
    for (int off = 32; off; off >>= 1){ int o = __shfl_xor(best, off); best = min(best, o); }
    if ((tid & 63) == 0) ridx[tid >> 6] = best;
    __syncthreads();
  }
  const int tok = min(min(ridx[0],ridx[1]),min(ridx[2],ridx[3])) + 1 + hi*25 + wi;
  const int layer = (g < 7) ? (24 - g*4) : 24;
  const float* src = feats + (((long)(b*NSEQ + tok))*LL + layer)*DD + tid*8;
  float4 a = *(const float4*)src;
  float4 c = *(const float4*)(src + 4);
  if (g == 7){
    uint4 o = { pk2bf(a.x,a.y), pk2bf(a.z,a.w), pk2bf(c.x,c.y), pk2bf(c.z,c.w) };
    *(uint4*)(A7 + (long)r*DD + tid*8) = o;
    return;
  }
  float s  = a.x+a.y+a.z+a.w + c.x+c.y+c.z+c.w;
  float qq = a.x*a.x+a.y*a.y+a.z*a.z+a.w*a.w + c.x*c.x+c.y*c.y+c.z*c.z+c.w*c.w;
  for (int off = 32; off; off >>= 1){ s += __shfl_xor(s, off); qq += __shfl_xor(qq, off); }
  const int wave = tid >> 6, lane = tid & 63;
  if (lane == 0){ rs[wave] = s; rq[wave] = qq; }
  __syncthreads();
  const float ts = rs[0]+rs[1]+rs[2]+rs[3];
  const float tq = rq[0]+rq[1]+rq[2]+rq[3];
  const float mu   = ts * (1.f/2048.f);
  const float var  = tq * (1.f/2048.f) - mu*mu;
  const float rstd = rsqrtf(var + 1e-5f);
  const float4 g0 = *(const float4*)(gamma + g*DD + tid*8);
  const float4 g1 = *(const float4*)(gamma + g*DD + tid*8 + 4);
  const float4 b0 = *(const float4*)(beta  + g*DD + tid*8);
  const float4 b1 = *(const float4*)(beta  + g*DD + tid*8 + 4);
  uint2 o;
  o.x = pk4_fp8(((a.x-mu)*rstd*g0.x + b0.x)*ASCALE, ((a.y-mu)*rstd*g0.y + b0.y)*ASCALE,
                ((a.z-mu)*rstd*g0.z + b0.z)*ASCALE, ((a.w-mu)*rstd*g0.w + b0.w)*ASCALE);
  o.y = pk4_fp8(((c.x-mu)*rstd*g1.x + b1.x)*ASCALE, ((c.y-mu)*rstd*g1.y + b1.y)*ASCALE,
                ((c.z-mu)*rstd*g1.z + b1.z)*ASCALE, ((c.w-mu)*rstd*g1.w + b1.w)*ASCALE);
  *(uint2*)(A8 + ((long)g*BHW + r)*DD + tid*8) = o;
}

// ---------- unified GEMM (launch 2 of 4): z=0..6 fp8 vis; z=7 inp bf16; z=8 clip bf16->fp32 ----------
__global__ __launch_bounds__(256, 3)
void gemm9_k(const u8* __restrict__ A8, const u8* __restrict__ B8,
             u16* __restrict__ C_all, const u16* __restrict__ A7,
             const u16* __restrict__ inpw, const u16* __restrict__ patch,
             const u16* __restrict__ clipw, float* __restrict__ cf,
             const float* __restrict__ input_b, const float* __restrict__ clip_b){
  __shared__ alignas(16) u8 smem[32768];
  const int z = blockIdx.z;
  const int bm = blockIdx.x*128, bn = blockIdx.y*128;
  const int tid = threadIdx.x, wave = tid >> 6, lane = tid & 63;
  const int l15 = lane & 15, quad = lane >> 4;
  const int wr = (wave >> 1)*64, wc = (wave & 1)*64;
  f32x4 acc[4][4] = {};
  const int laneRow   = lane >> 3;
  const int laneChunk = (lane & 7) ^ laneRow;

  if (z < 7){
    // ---- MX-fp8, BK=128, XOR-16B-chunk swizzle, identity E8M0 scales ----
    u8* As = smem;
    u8* Bs = smem + 16384;
    const u8* Az = A8 + (long)z*BHW*DD;
    const u8* Bz = B8 + (long)z*CLIPC*DD;
    const u8* gA = Az + (long)(bm + wave*32 + laneRow)*DD + laneChunk*16;
    const u8* gB = Bz + (long)(bn + wave*32 + laneRow)*DD + laneChunk*16;
    u8* lA = &As[wave*32*128];
    u8* lB = &Bs[wave*32*128];
    const long rs8 = 8L*DD;
    for (int k0 = 0; k0 < DD; k0 += 128){
#pragma unroll
      for (int t = 0; t < 4; t++) gld_lds16(gA + k0 + t*rs8, lA + t*1024);
#pragma unroll
      for (int t = 0; t < 4; t++) gld_lds16(gB + k0 + t*rs8, lB + t*1024);
      __syncthreads();
      i32x8 af[4], bg[4];
      const int sw = l15 & 7;
#pragma unroll
      for (int i = 0; i < 4; i++){
        const u8* rp = &As[(wr + i*16 + l15)*128];
        uint4 lo = *(const uint4*)(rp + (((quad*2 + 0) ^ sw)*16));
        uint4 hi = *(const uint4*)(rp + (((quad*2 + 1) ^ sw)*16));
        af[i] = (i32x8){(int)lo.x,(int)lo.y,(int)lo.z,(int)lo.w,
                        (int)hi.x,(int)hi.y,(int)hi.z,(int)hi.w};
      }
#pragma unroll
      for (int j = 0; j < 4; j++){
        const u8* rp = &Bs[(wc + j*16 + l15)*128];
        uint4 lo = *(const uint4*)(rp + (((quad*2 + 0) ^ sw)*16));
        uint4 hi = *(const uint4*)(rp + (((quad*2 + 1) ^ sw)*16));
        bg[j] = (i32x8){(int)lo.x,(int)lo.y,(int)lo.z,(int)lo.w,
                        (int)hi.x,(int)hi.y,(int)hi.z,(int)hi.w};
      }
#pragma unroll
      for (int i = 0; i < 4; i++)
#pragma unroll
        for (int j = 0; j < 4; j++)
          acc[i][j] = __builtin_amdgcn_mfma_scale_f32_16x16x128_f8f6f4(
              af[i], bg[j], acc[i][j], 0, 0, 0, 0x7F7F7F7F, 0, 0x7F7F7F7F);
      __syncthreads();
    }
    u16* C = C_all + (long)z*BHW*CLIPC;
#pragma unroll
    for (int i = 0; i < 4; i++)
#pragma unroll
      for (int j = 0; j < 4; j++)
#pragma unroll
        for (int rr = 0; rr < 4; rr++){
          const int row = bm + wr + i*16 + quad*4 + rr;
          const int col = bn + wc + j*16 + l15;
          C[(long)row*CLIPC + col] = f2bf(acc[i][j][rr] * INV_AB);
        }
  } else {
    // ---- bf16, BK=64, XOR swizzle ----
    u16* As = (u16*)smem;
    u16* Bs = (u16*)(smem + 16384);
    const u16* Az = (z == 7) ? A7   : patch;
    const u16* Bz = (z == 7) ? inpw : clipw;
    const int K  = (z == 7) ? DD : KPAD;
    const int laneCol = laneChunk * 8;
    const u16* gA = Az + (long)(bm + wave*32 + laneRow)*K + laneCol;
    const u16* gB = Bz + (long)(bn + wave*32 + laneRow)*K + laneCol;
    u16* lA = &As[wave*2048];
    u16* lB = &Bs[wave*2048];
    const long rs8 = (long)8 * K;
    for (int k0 = 0; k0 < K; k0 += 64){
#pragma unroll
      for (int t = 0; t < 4; t++) gld_lds16(gA + k0 + t*rs8, lA + t*512);
#pragma unroll
      for (int t = 0; t < 4; t++) gld_lds16(gB + k0 + t*rs8, lB + t*512);
      __syncthreads();
#pragma unroll
      for (int s = 0; s < 2; s++){
        bf16x8 af[4], bg[4];
#pragma unroll
        for (int i = 0; i < 4; i++)
          af[i] = *(const bf16x8*)&As[(wr + i*16 + l15)*64 + (((s*4 + quad) ^ (l15 & 7))*8)];
#pragma unroll
        for (int j = 0; j < 4; j++)
          bg[j] = *(const bf16x8*)&Bs[(wc + j*16 + l15)*64 + (((s*4 + quad) ^ (l15 & 7))*8)];
#pragma unroll
        for (int i = 0; i < 4; i++)
#pragma unroll
          for (int j = 0; j < 4; j++)
            acc[i][j] = __builtin_amdgcn_mfma_f32_16x16x32_bf16(af[i], bg[j], acc[i][j], 0, 0, 0);
      }
      __syncthreads();
    }
    if (z == 7){
      u16* C = C_all + 7L*BHW*CLIPC;
#pragma unroll
      for (int i = 0; i < 4; i++)
#pragma unroll
        for (int j = 0; j < 4; j++)
#pragma unroll
          for (int rr = 0; rr < 4; rr++){
            const int row = bm + wr + i*16 + quad*4 + rr;
            const int col = bn + wc + j*16 + l15;
            C[(long)row*CLIPC + col] = f2bf(acc[i][j][rr] + input_b[col]);
          }
    } else {
#pragma unroll
      for (int i = 0; i < 4; i++)
#pragma unroll
        for (int j = 0; j < 4; j++)
#pragma unroll
          for (int rr = 0; rr < 4; rr++){
            const int row = bm + wr + i*16 + quad*4 + rr;
            const int col = bn + wc + j*16 + l15;
            cf[(long)row*CLIPC + col] = acc[i][j][rr] + clip_b[col];
          }
    }
  }
}

// ---------- attention (launch 3 of 4): 256 threads = 4 heads ----------
__global__ void attn_k(const u16* __restrict__ C_all, u16* __restrict__ fuse){
  const int r = blockIdx.x;
  const int h = (blockIdx.y << 2) | (threadIdx.x >> 6);
  const int lane = threadIdx.x & 63;
  const long slot = (long)BHW * CLIPC;
  const long rb = (long)r * CLIPC;
  const int c0 = h*128 + lane, c1 = c0 + 64;
  const float q0 = bf2f(C_all[rb + c0]), q1 = bf2f(C_all[rb + c1]);
  float k0v[6], k1v[6], dt[6];
#pragma unroll
  for (int t = 0; t < 6; t++){
    const u16* base = C_all + (long)(t+1)*slot + rb;
    k0v[t] = bf2f(base[c0]); k1v[t] = bf2f(base[c1]);
    dt[t] = q0*k0v[t] + q1*k1v[t];
  }
#pragma unroll
  for (int t = 0; t < 6; t++)
    for (int off = 32; off; off >>= 1) dt[t] += __shfl_xor(dt[t], off);
  float l[6], e[6];
#pragma unroll
  for (int t = 0; t < 6; t++) l[t] = dt[t] * 0.03125f;
  float m = l[0];
#pragma unroll
  for (int t = 1; t < 6; t++) m = fmaxf(m, l[t]);
  float ssum = 0.f;
#pragma unroll
  for (int t = 0; t < 6; t++){ e[t] = __expf(l[t] - m); ssum += e[t]; }
  const float inv = 1.f / ssum;
  float f0 = 0.f, f1 = 0.f;
#pragma unroll
  for (int t = 0; t < 6; t++){ const float a = e[t]*inv; f0 += a*k0v[t]; f1 += a*k1v[t]; }
  fuse[rb + c0] = f2bf(f0);
  fuse[rb + c1] = f2bf(f1);
}

// ---------- output GEMM + cosine partials + last-block final loss (launch 4 of 4) ----------
__global__ __launch_bounds__(256, 3)
void gemm_out_k(const u16* __restrict__ fuse, const u16* __restrict__ outw,
                const u16* __restrict__ inp, const float* __restrict__ output_b,
                const float* __restrict__ cf, float* __restrict__ rowacc,
                unsigned int* __restrict__ done, float* __restrict__ out){
  __shared__ alignas(16) u8 smem[32768];
  u16* As = (u16*)smem;
  u16* Bs = (u16*)(smem + 16384);
  const int bm = blockIdx.x*128, bn = blockIdx.y*128;
  const int tid = threadIdx.x, wave = tid >> 6, lane = tid & 63;
  const int l15 = lane & 15, quad = lane >> 4;
  const int wr = (wave >> 1)*64, wc = (wave & 1)*64;
  f32x4 acc[4][4] = {};
  {
    const int laneRow = lane >> 3;
    const int laneCol = (((lane & 7) ^ laneRow) * 8);
    const u16* gA = fuse + (long)(bm + wave*32 + laneRow)*CLIPC + laneCol;
    const u16* gB = outw + (long)(bn + wave*32 + laneRow)*CLIPC + laneCol;
    u16* lA = &As[wave*2048];
    u16* lB = &Bs[wave*2048];
    const long rs8 = 8L*CLIPC;
    for (int k0 = 0; k0 < CLIPC; k0 += 64){
#pragma unroll
      for (int t = 0; t < 4; t++) gld_lds16(gA + k0 + t*rs8, lA + t*512);
#pragma unroll
      for (int t = 0; t < 4; t++) gld_lds16(gB + k0 + t*rs8, lB + t*512);
      __syncthreads();
#pragma unroll
      for (int s = 0; s < 2; s++){
        bf16x8 af[4], bg[4];
#pragma unroll
        for (int i = 0; i < 4; i++)
          af[i] = *(const bf16x8*)&As[(wr + i*16 + l15)*64 + (((s*4 + quad) ^ (l15 & 7))*8)];
#pragma unroll
        for (int j = 0; j < 4; j++)
          bg[j] = *(const bf16x8*)&Bs[(wc + j*16 + l15)*64 + (((s*4 + quad) ^ (l15 & 7))*8)];
#pragma unroll
        for (int i = 0; i < 4; i++)
#pragma unroll
          for (int j = 0; j < 4; j++)
            acc[i][j] = __builtin_amdgcn_mfma_f32_16x16x32_bf16(af[i], bg[j], acc[i][j], 0, 0, 0);
      }
      __syncthreads();
    }
  }
#pragma unroll
  for (int i = 0; i < 4; i++)
#pragma unroll
    for (int rr = 0; rr < 4; rr++){
      const int row = bm + wr + i*16 + quad*4 + rr;
      float soc = 0.f, soo = 0.f, scc = 0.f;
#pragma unroll
      for (int j = 0; j < 4; j++){
        const int col = bn + wc + j*16 + l15;
        const long p = (long)row*CLIPC + col;
        const float o = acc[i][j][rr] + output_b[col] + bf2f(inp[p]);
        const float c = cf[p];
        soc += o*c; soo += o*o; scc += c*c;
      }
#pragma unroll
      for (int off = 1; off < 16; off <<= 1){
        soc += __shfl_xor(soc, off); soo += __shfl_xor(soo, off); scc += __shfl_xor(scc, off);
      }
      if (l15 == 0){
        atomicAdd(&rowacc[row*4 + 0], soc);
        atomicAdd(&rowacc[row*4 + 1], soo);
        atomicAdd(&rowacc[row*4 + 2], scc);
      }
    }
  // ---- last block computes the final loss ----
  __threadfence();
  __shared__ unsigned int amLast;
  if (tid == 0) amLast = (atomicAdd(done, 1u) == 71u) ? 1u : 0u;
  __syncthreads();
  if (!amLast) return;
  float s = 0.f;
  for (int r = tid; r < BHW; r += 256){
    const float soc = __hip_atomic_load(&rowacc[r*4+0], __ATOMIC_RELAXED, __HIP_MEMORY_SCOPE_AGENT);
    const float soo = __hip_atomic_load(&rowacc[r*4+1], __ATOMIC_RELAXED, __HIP_MEMORY_SCOPE_AGENT);
    const float scc = __hip_atomic_load(&rowacc[r*4+2], __ATOMIC_RELAXED, __HIP_MEMORY_SCOPE_AGENT);
    s += soc / fmaxf(sqrtf(soo*scc), 1e-8f);
  }
  for (int off = 32; off; off >>= 1) s += __shfl_xor(s, off);
  __shared__ float fr[4];
  if ((tid & 63) == 0) fr[tid >> 6] = s;
  __syncthreads();
  if (tid == 0) out[0] = 1.f - (fr[0]+fr[1]+fr[2]+fr[3]) * (1.f/(float)BHW);
}

extern "C" void kernel_launch(void* const* d_in, const int* in_sizes, int n_in,
                              void* d_out, int out_size, void* d_ws, size_t ws_size,
                              hipStream_t stream){
  const int*   input_ids = (const int*)  d_in[0];
  const float* images    = (const float*)d_in[1];
  const float* all_feats = (const float*)d_in[2];
  const float* norm_gamma = (const float*)d_in[4];
  const float* norm_beta  = (const float*)d_in[5];
  const float* norm_w     = (const float*)d_in[6];
  const float* input_w    = (const float*)d_in[7];
  const float* input_b    = (const float*)d_in[8];
  const float* output_w   = (const float*)d_in[9];
  const float* output_b   = (const float*)d_in[10];
  const float* clip_w     = (const float*)d_in[11];
  const float* clip_b     = (const float*)d_in[12];
  float* out = (float*)d_out;

  // ---- workspace layout (~75 MB) ----
  char* w = (char*)d_ws;
  unsigned int* done = (unsigned int*)w;
  size_t off = 256;
  u8*  A8    = (u8*) (w + off); off += 7L*BHW*DD;
  u16* A7    = (u16*)(w + off); off += (long)BHW*DD*2;
  u8*  B8    = (u8*) (w + off); off += 7L*CLIPC*DD;
  u16* inpw  = (u16*)(w + off); off += (long)CLIPC*DD*2;
  u16* outw  = (u16*)(w + off); off += (long)CLIPC*CLIPC*2;
  u16* clipw = (u16*)(w + off); off += (long)CLIPC*KPAD*2;
  u16* patch = (u16*)(w + off); off += (long)BHW*KPAD*2;
  u16* C_all = (u16*)(w + off); off += 8L*BHW*CLIPC*2;
  u16* fuse  = (u16*)(w + off); off += (long)BHW*CLIPC*2;
  float* cf     = (float*)(w + off); off += (long)BHW*CLIPC*4;
  float* rowacc = (float*)(w + off); off += (long)BHW*4*4;

  prep_k<<<20096, 256, 0, stream>>>(norm_w, input_w, output_w, clip_w, images, all_feats,
                                    input_ids, norm_gamma, norm_beta,
                                    B8, inpw, outw, clipw, patch, A8, A7, rowacc, done);
  gemm9_k<<<dim3(9, 8, 9), 256, 0, stream>>>(A8, B8, C_all, A7, inpw, patch, clipw, cf,
                                             input_b, clip_b);
  attn_k<<<dim3(1152, 2), 256, 0, stream>>>(C_all, fuse);
  gemm_out_k<<<dim3(9, 8), 256, 0, stream>>>(fuse, outw, C_all + 7L*BHW*CLIPC,
                                             output_b, cf, rowacc, done, out);
}